// Round 13
// baseline (2305.636 us; speedup 1.0000x reference)
//
#include <hip/hip_runtime.h>
#include <cstdint>

#define NS 2048      // states S
#define NE 65536     // arcs E
#define ND 2048      // pdfs D
#define NB 32        // batch
#define NT 500       // frames
#define NGROUPS 32   // 64-state dest groups
#define ELLCAP (2*NE)   // uint4 entries; padded total ~102K < 131072
#define LEAKYF 0.1f
#define NBG 16       // batch groups (2 batches each)
#define NSP 32       // state partitions (64 states each) -> 512 WGs, 2/CU

// ws byte offsets
#define WS_COUNTS 0
#define WS_CURSOR 8192
#define WS_WIDTHS 16384
#define WS_GBASE  16640
#define WS_ALBUF  20480      // 2 par x 16 bg x 2048 x 8B = 512 KB
#define WS_ARC    544768     // ELLCAP * 16B = 2 MB

typedef float __attribute__((ext_vector_type(2))) f2v;

// ---- agent-scope (L3 coherence point) ops: the ONLY working exchange scope ----
__device__ __forceinline__ void ld4_l3(const float2* p0, const float2* p1,
                                       const float2* p2, const float2* p3,
                                       float2& r0, float2& r1, float2& r2, float2& r3) {
    f2v a, b, c, d;
    asm volatile("global_load_dwordx2 %0, %4, off sc0 sc1\n\t"
                 "global_load_dwordx2 %1, %5, off sc0 sc1\n\t"
                 "global_load_dwordx2 %2, %6, off sc0 sc1\n\t"
                 "global_load_dwordx2 %3, %7, off sc0 sc1\n\t"
                 "s_waitcnt vmcnt(0)"
                 : "=&v"(a), "=&v"(b), "=&v"(c), "=&v"(d)
                 : "v"(p0), "v"(p1), "v"(p2), "v"(p3) : "memory");
    r0 = make_float2(a.x, a.y); r1 = make_float2(b.x, b.y);
    r2 = make_float2(c.x, c.y); r3 = make_float2(d.x, d.y);
}
__device__ __forceinline__ void st2_l3(float2* p, float2 v) {
    f2v d; d.x = v.x; d.y = v.y;
    asm volatile("global_store_dwordx2 %0, %1, off sc0 sc1"
                 :: "v"(p), "v"(d) : "memory");
}
__device__ __forceinline__ uint32_t sgn(float v, uint32_t sexp) {
    return (__float_as_uint(v) >> 31) ^ sexp;
}

__global__ void k_init(const float* __restrict__ log_init, float* albuf, float* out,
                       uint32_t* counts, uint32_t* cursor, uint4* arcp) {
    int tid = blockIdx.x * blockDim.x + threadIdx.x;
    int n = blockDim.x * gridDim.x;
    for (int i = tid; i < NS; i += n) { counts[i] = 0u; cursor[i] = 0u; }
    for (int i = tid; i < ELLCAP; i += n) arcp[i] = make_uint4(0u, 0u, 0u, 0u);
    float2* ab = reinterpret_cast<float2*>(albuf);
    const int PL = NBG * NS;
    for (int i = tid; i < PL; i += n) {
        int s = i & (NS - 1);
        float a = __expf(log_init[s]);
        ab[i]      = make_float2(a, a);        // parity0 = epoch 0, sign +
        ab[PL + i] = make_float2(-1.f, -1.f);  // parity1 sentinel: stale for epoch 1
    }
    if (tid == 0) out[0] = 0.0f;
}

__global__ void k_count(const int* __restrict__ to_state, uint32_t* counts) {
    int e = blockIdx.x * blockDim.x + threadIdx.x;
    if (e < NE) atomicAdd(&counts[to_state[e]], 1u);
}

__global__ void k_widths(const uint32_t* __restrict__ counts, uint32_t* widths, uint32_t* gbase) {
    int g = threadIdx.x;
    if (g < NGROUPS) {
        uint32_t w = 0u;
        for (int i = 0; i < 64; ++i) w = max(w, counts[g*64 + i]);
        widths[g] = w;
    }
    __syncthreads();
    if (threadIdx.x == 0) {
        uint32_t acc = 0u;
        for (int g2 = 0; g2 < NGROUPS; ++g2) { gbase[g2] = acc; acc += widths[g2] * 64u; }
        gbase[NGROUPS] = acc;
    }
}

__global__ void k_scatter(const int* __restrict__ from_state, const int* __restrict__ to_state,
                          const int* __restrict__ pdf_ids, const float* __restrict__ log_w,
                          const float* __restrict__ log_init,
                          const uint32_t* __restrict__ gbase, uint32_t* cursor, uint4* arcp) {
    int e = blockIdx.x * blockDim.x + threadIdx.x;
    if (e >= NE) return;
    int s = to_state[e];
    int g = s >> 6;
    uint32_t slot = atomicAdd(&cursor[s], 1u);
    uint32_t pos = gbase[g] + slot * 64u + (uint32_t)(s & 63);
    int fs = from_state[e];
    uint32_t meta = (uint32_t)fs | ((uint32_t)pdf_ids[e] << 16);
    float w  = __expf(log_w[e]);
    float w2 = LEAKYF * __expf(log_init[fs]) * w;   // leaky-path weight
    arcp[pos] = make_uint4(meta, __float_as_uint(w), __float_as_uint(w2), 0u);
}

// 512 persistent WGs of 512 threads (2 co-resident per CU, different batch-groups):
// when one WG stalls on the L3 rendezvous, the other's 8 waves keep the CU busy.
// bid = sp*16 + bg -> bid%8 = bg%8 (XCD-locked). Sign-epoch protocol (R10).
__global__ __launch_bounds__(512, 4) void k_fwd(
    const float* __restrict__ x, const float* __restrict__ log_final,
    const uint4* __restrict__ arc, const uint32_t* __restrict__ widths,
    const uint32_t* __restrict__ gbase,
    float* albuf, float* out)
{
    __shared__ __align__(16) float2 e2[NS];        // 16 KB raw alpha
    __shared__ __align__(16) float2 Xs[2 * ND];    // 32 KB exp(x) double-buffered
    __shared__ __align__(16) float2 pt[8 * 64];    // 4 KB partials
    __shared__ __align__(16) float2 red[8];

    const int tid  = threadIdx.x;
    const int bg   = blockIdx.x & 15;
    const int sp   = blockIdx.x >> 4;
    const int lane = tid & 63;
    const int wid  = tid >> 6;              // 0..7

    const float* x0 = x + (size_t)(bg * 2)     * NT * ND;
    const float* x1 = x + (size_t)(bg * 2 + 1) * NT * ND;

    // Xs[0] prologue: 4 entries per thread
    #pragma unroll
    for (int k = 0; k < 4; ++k) {
        int idx = tid + k * 512;
        Xs[idx] = make_float2(__expf(x0[idx]), __expf(x1[idx]));
    }

    const int wd = (int)widths[sp];
    const uint4* ap = arc + gbase[sp] + lane;    // slot i at ap[i*64]
    float2* albuf2 = reinterpret_cast<float2*>(albuf);
    const int PL = NBG * NS;

    float C0 = 0.f, C1 = 0.f;

    for (int t = 0; t < NT; ++t) {
        const int par = t & 1;
        const float2* cbuf = albuf2 + (size_t)par * PL + (size_t)bg * NS;
        float2*       nbuf = albuf2 + (size_t)(par ^ 1) * PL + (size_t)bg * NS;
        float2* Xcur = Xs + (size_t)par * ND;
        float2* Xnxt = Xs + (size_t)(par ^ 1) * ND;
        const uint32_t sexp = (uint32_t)((t >> 1) & 1);

        // spin-load alpha_t: 4 float2 per thread (states tid+k*512)
        float2 A0, A1, A2, A3;
        for (;;) {
            ld4_l3(cbuf + tid, cbuf + tid + 512, cbuf + tid + 1024, cbuf + tid + 1536,
                   A0, A1, A2, A3);
            uint32_t m = sgn(A0.x, sexp) | sgn(A0.y, sexp)
                       | sgn(A1.x, sexp) | sgn(A1.y, sexp)
                       | sgn(A2.x, sexp) | sgn(A2.y, sexp)
                       | sgn(A3.x, sexp) | sgn(A3.y, sexp);
            if (m == 0u) break;
            __builtin_amdgcn_s_sleep(1);
        }
        A0.x = fabsf(A0.x); A0.y = fabsf(A0.y);
        A1.x = fabsf(A1.x); A1.y = fabsf(A1.y);
        A2.x = fabsf(A2.x); A2.y = fabsf(A2.y);
        A3.x = fabsf(A3.x); A3.y = fabsf(A3.y);

        // x(t+1) prefetch (plain cached loads; consumed after arc pass)
        float pa[4], pb[4];
        const bool pf = (t + 1 < NT);
        if (pf) {
            const size_t o = (size_t)(t + 1) * ND;
            #pragma unroll
            for (int k = 0; k < 4; ++k) {
                pa[k] = x0[o + tid + k * 512];
                pb[k] = x1[o + tid + k * 512];
            }
        }

        e2[tid]        = A0;
        e2[tid + 512]  = A1;
        e2[tid + 1024] = A2;
        e2[tid + 1536] = A3;
        float u0 = A0.x + A1.x + A2.x + A3.x;
        float u1 = A0.y + A1.y + A2.y + A3.y;
        #pragma unroll
        for (int off = 32; off > 0; off >>= 1) {
            u0 += __shfl_down(u0, off, 64);
            u1 += __shfl_down(u1, off, 64);
        }
        if (lane == 0) red[wid] = make_float2(u0, u1);
        __syncthreads();   // (B2): e2 + red + Xs[par] ready

        float T0 = 0.f, T1 = 0.f;
        #pragma unroll
        for (int j = 0; j < 8; ++j) { float2 q = red[j]; T0 += q.x; T1 += q.y; }
        const float i0 = 1.0f / T0, i1 = 1.0f / T1;
        if (tid == 0) { C0 += __logf(T0); C1 += __logf(T1); }

        // arc pass: out = sum X[pdf] * (a[src]*invT*w + w2); 8-wave slot slicing
        float2 acc = make_float2(0.f, 0.f);
        for (int i = wid; i < wd; i += 8) {
            uint4 A = ap[(size_t)i * 64];
            const float w  = __uint_as_float(A.y);
            const float w2 = __uint_as_float(A.z);
            const int src = (int)(A.x & 0xFFFFu);
            const int pdf = (int)(A.x >> 16);
            float2 ev = e2[src];
            float2 xv = Xcur[pdf];
            acc.x = fmaf(xv.x, fmaf(ev.x * i0, w, w2), acc.x);
            acc.y = fmaf(xv.y, fmaf(ev.y * i1, w, w2), acc.y);
        }
        pt[wid * 64 + lane] = acc;
        if (pf) {
            #pragma unroll
            for (int k = 0; k < 4; ++k)
                Xnxt[tid + k * 512] = make_float2(__expf(pa[k]), __expf(pb[k]));
        }
        __syncthreads();   // (C): pt ready

        // wave-0 tail: reduce 8 partials for 64 states, fire-and-forget signed store.
        // Other 7 waves fall through to the t+1 spin immediately.
        if (wid == 0) {
            float2 r = pt[lane];
            #pragma unroll
            for (int k = 1; k < 8; ++k) {
                float2 q = pt[k * 64 + lane];
                r.x += q.x; r.y += q.y;
            }
            const float sg = (((t + 1) >> 1) & 1) ? -1.f : 1.f;
            st2_l3(nbuf + sp * 64 + lane, make_float2(r.x * sg, r.y * sg));
        }
    }
    __syncthreads();

    // epilogue: sp==0 WG per batch-group; epoch NT=500: parity 0, sign +
    if (sp == 0) {
        const float2* fbuf = albuf2 + (size_t)bg * NS;
        const uint32_t sexp = (uint32_t)((NT >> 1) & 1);
        float2 A0, A1, A2, A3;
        for (;;) {
            ld4_l3(fbuf + tid, fbuf + tid + 512, fbuf + tid + 1024, fbuf + tid + 1536,
                   A0, A1, A2, A3);
            uint32_t m = sgn(A0.x, sexp) | sgn(A0.y, sexp)
                       | sgn(A1.x, sexp) | sgn(A1.y, sexp)
                       | sgn(A2.x, sexp) | sgn(A2.y, sexp)
                       | sgn(A3.x, sexp) | sgn(A3.y, sexp);
            if (m == 0u) break;
            __builtin_amdgcn_s_sleep(1);
        }
        float u0 = 0.f, u1 = 0.f;
        #pragma unroll
        for (int k = 0; k < 4; ++k) {
            float2 A = (k == 0) ? A0 : (k == 1) ? A1 : (k == 2) ? A2 : A3;
            float f = __expf(log_final[tid + k * 512]);
            u0 += fabsf(A.x) * f;
            u1 += fabsf(A.y) * f;
        }
        #pragma unroll
        for (int off = 32; off > 0; off >>= 1) {
            u0 += __shfl_down(u0, off, 64);
            u1 += __shfl_down(u1, off, 64);
        }
        if (lane == 0) red[wid] = make_float2(u0, u1);
        __syncthreads();
        if (tid == 0) {
            float t0 = 0.f, t1 = 0.f;
            #pragma unroll
            for (int j = 0; j < 8; ++j) { t0 += red[j].x; t1 += red[j].y; }
            atomicAdd(out, -(__logf(t0) + C0) - (__logf(t1) + C1));
        }
    }
}

extern "C" void kernel_launch(void* const* d_in, const int* in_sizes, int n_in,
                              void* d_out, int out_size, void* d_ws, size_t ws_size,
                              hipStream_t stream) {
    const float* x         = (const float*)d_in[0];
    const float* log_w     = (const float*)d_in[1];
    const float* log_init  = (const float*)d_in[2];
    const float* log_final = (const float*)d_in[3];
    const int*   from_st   = (const int*)d_in[4];
    const int*   to_st     = (const int*)d_in[5];
    const int*   pdf_ids   = (const int*)d_in[6];
    float* out = (float*)d_out;

    uint8_t* ws = (uint8_t*)d_ws;
    uint32_t* counts = (uint32_t*)(ws + WS_COUNTS);
    uint32_t* cursor = (uint32_t*)(ws + WS_CURSOR);
    uint32_t* widths = (uint32_t*)(ws + WS_WIDTHS);
    uint32_t* gbase  = (uint32_t*)(ws + WS_GBASE);
    float*    albuf  = (float*)(ws + WS_ALBUF);
    uint4*    arc    = (uint4*)(ws + WS_ARC);

    k_init   <<<512, 256, 0, stream>>>(log_init, albuf, out, counts, cursor, arc);
    k_count  <<<NE/256, 256, 0, stream>>>(to_st, counts);
    k_widths <<<1, 64, 0, stream>>>(counts, widths, gbase);
    k_scatter<<<NE/256, 256, 0, stream>>>(from_st, to_st, pdf_ids, log_w, log_init,
                                          gbase, cursor, arc);
    k_fwd    <<<NSP*NBG, 512, 0, stream>>>(x, log_final, arc, widths, gbase,
                                           albuf, out);
}